// Round 6
// baseline (174.254 us; speedup 1.0000x reference)
//
#include <hip/hip_runtime.h>
#include <stdint.h>

// Problem dims: x(4,2048,512) W1(512,1024) b1(1024) Wq(1024,1024) A=16 — fp32 in, fp32 out
constexpr int BATCH = 4;
constexpr int SEQ   = 2048;
constexpr int DIN   = 512;
constexpr int DH    = 1024;
constexpr int BS    = BATCH * SEQ;  // 8192
constexpr int AP    = 32;           // attn positions per block
constexpr int AW    = 64;           // attn window rows (AP + 2*16)

typedef float  floatx4 __attribute__((ext_vector_type(4)));
typedef short  bf16x8  __attribute__((ext_vector_type(8)));

static __device__ __forceinline__ unsigned short f2bf(float f) {
  union { float f; unsigned u; } v; v.f = f;
  unsigned r = (v.u + 0x7fffu + ((v.u >> 16) & 1u)) >> 16;  // RNE
  return (unsigned short)r;
}

// async global->LDS, 16B per lane; LDS dest is wave-uniform base + lane*16
static __device__ __forceinline__ void gld_lds16(const unsigned short* g, const short* l) {
  typedef const __attribute__((address_space(1))) void* gvp;
  typedef __attribute__((address_space(3))) void* lvp;
  __builtin_amdgcn_global_load_lds((gvp)(uintptr_t)g, (lvp)(unsigned)(uintptr_t)l, 16, 0, 0);
}

// ---------------- elementwise fp32 -> bf16 ----------------
__global__ __launch_bounds__(256) void to_bf16_k(const float* __restrict__ in,
                                                 unsigned short* __restrict__ out, int n) {
  int i = (blockIdx.x * 256 + threadIdx.x) * 4;
  if (i < n) {
    float4 v = *(const float4*)(in + i);
    ushort4 o;
    o.x = f2bf(v.x); o.y = f2bf(v.y); o.z = f2bf(v.z); o.w = f2bf(v.w);
    *(ushort4*)(out + i) = o;
  }
}

// ---------------- transpose fp32 (R x C) -> bf16 (C x R) ----------------
__global__ __launch_bounds__(256) void transpose_bf16_k(const float* __restrict__ in,
                                                        unsigned short* __restrict__ out,
                                                        int R, int C) {
  __shared__ float t[32][33];
  int c0 = blockIdx.x * 32, r0 = blockIdx.y * 32;
  int tx = threadIdx.x & 31, ty = threadIdx.x >> 5;  // 32 x 8
  for (int i = ty; i < 32; i += 8) t[i][tx] = in[(size_t)(r0 + i) * C + c0 + tx];
  __syncthreads();
  for (int i = ty; i < 32; i += 8) out[(size_t)(c0 + i) * R + r0 + tx] = f2bf(t[tx][i]);
}

// ---------------- transpose bf16 [BS][DH] -> [DH][BS], 64x64 tiles ----------------
__global__ __launch_bounds__(256) void transpose_hb_k(const unsigned short* __restrict__ in,
                                                      unsigned short* __restrict__ out) {
  __shared__ __align__(16) unsigned short t[64][80];
  const int tid = threadIdx.x;
  const int r0 = blockIdx.x * 64;  // BS dim
  const int c0 = blockIdx.y * 64;  // DH dim
  const int tr = tid >> 2, tc = (tid & 3) * 16;
  const uint4* src = (const uint4*)(in + (size_t)(r0 + tr) * DH + c0 + tc);
  uint4 v0 = src[0], v1 = src[1];
  *(uint4*)&t[tr][tc]     = v0;
  *(uint4*)&t[tr][tc + 8] = v1;
  __syncthreads();
  __align__(16) unsigned short vals[16];
  #pragma unroll
  for (int e = 0; e < 16; e++) vals[e] = t[tc + e][tr];
  uint4* dst = (uint4*)(out + (size_t)(c0 + tr) * BS + r0 + tc);
  dst[0] = ((uint4*)vals)[0];
  dst[1] = ((uint4*)vals)[1];
}

// ---------------- bf16 MFMA GEMM: C[MxN] = A[MxK] * B[KxN], B given as B^T (NxK) ---------
template <bool RELU>
__global__ __launch_bounds__(256) void gemm_bt(const unsigned short* __restrict__ Ab,
                                               const unsigned short* __restrict__ Bt,
                                               const float* __restrict__ bias,
                                               unsigned short* __restrict__ outB,
                                               int M, int N, int K) {
  __shared__ __align__(16) short As[128 * 32];
  __shared__ __align__(16) short Bs[128 * 32];
  const int tid  = threadIdx.x;
  const int m0   = blockIdx.y * 128, n0 = blockIdx.x * 128;
  const int wv   = tid >> 6, lane = tid & 63;
  const int wm   = (wv >> 1) * 64, wn = (wv & 1) * 64;
  const int l16  = lane & 15, quad = lane >> 4;

  const int ra = lane >> 2;
  const int ca = (lane & 3) * 8;
  const unsigned short* gA0 = Ab + (size_t)(m0 + wv * 32 + ra) * K + ca;
  const unsigned short* gA1 = Ab + (size_t)(m0 + wv * 32 + 16 + ra) * K + ca;
  const unsigned short* gB0 = Bt + (size_t)(n0 + wv * 32 + ra) * K + ca;
  const unsigned short* gB1 = Bt + (size_t)(n0 + wv * 32 + 16 + ra) * K + ca;
  const short* lA0 = &As[wv * 1024];
  const short* lA1 = &As[wv * 1024 + 512];
  const short* lB0 = &Bs[wv * 1024];
  const short* lB1 = &Bs[wv * 1024 + 512];

  floatx4 acc[4][4];
  for (int i = 0; i < 4; i++)
    for (int j = 0; j < 4; j++) acc[i][j] = {0.f, 0.f, 0.f, 0.f};

  const int ksteps = K >> 5;
  for (int ks = 0; ks < ksteps; ++ks) {
    __syncthreads();
    gld_lds16(gA0, lA0); gld_lds16(gA1, lA1);
    gld_lds16(gB0, lB0); gld_lds16(gB1, lB1);
    gA0 += 32; gA1 += 32; gB0 += 32; gB1 += 32;
    __syncthreads();
    bf16x8 af[4], bfr[4];
    for (int i = 0; i < 4; i++)
      af[i] = *(const bf16x8*)&As[(wm + i * 16 + l16) * 32 + quad * 8];
    for (int j = 0; j < 4; j++)
      bfr[j] = *(const bf16x8*)&Bs[(wn + j * 16 + l16) * 32 + quad * 8];
    for (int i = 0; i < 4; i++)
      for (int j = 0; j < 4; j++)
        acc[i][j] = __builtin_amdgcn_mfma_f32_16x16x32_bf16(af[i], bfr[j], acc[i][j], 0, 0, 0);
  }

  for (int j = 0; j < 4; j++) {
    const int col = n0 + wn + j * 16 + l16;
    const float bv = RELU ? bias[col] : 0.f;
    for (int i = 0; i < 4; i++) {
      const int rowb = m0 + wm + i * 16 + quad * 4;
      for (int r = 0; r < 4; r++) {
        float v = acc[i][j][r] + bv;
        if (RELU) v = fmaxf(v, 0.f);
        outB[(size_t)(rowb + r) * N + col] = f2bf(v);
      }
    }
  }
}

// ---------------- barrier-free MFMA banded attention ----------------
// Block: 512 threads (8 waves), AP=32 positions, window AW=64 rows.
// QK: fragments loaded straight from global (qb, hb) -> 1 16x16 score tile/wave.
// Softmax via LDS (2 barriers total). PV computed transposed: A = hbT frag (m=dh),
// B = P frag (n=pos) -> coalesced float4 stores of out.
__global__ __launch_bounds__(512) void attn_mfma_k(const unsigned short* __restrict__ hb,
                                                   const unsigned short* __restrict__ hbT,
                                                   const unsigned short* __restrict__ qb,
                                                   float* __restrict__ out) {
  __shared__ float Sf[32 * 64];                // raw scores
  __shared__ __align__(16) short Ps[32 * 72];  // softmax weights, row=pos, col=window k

  const int tid  = threadIdx.x;
  const int wave = tid >> 6, lane = tid & 63;
  const int l16  = lane & 15, quad = lane >> 4;
  const int p0   = blockIdx.x * AP;
  const int s0   = p0 & (SEQ - 1);

  // zero Ps (invalid band entries must contribute 0 to PV)
  for (int i = tid; i < 32 * 72 / 2; i += 512) ((unsigned*)Ps)[i] = 0;

  // ---------- QK: S[32x64], wave -> tile (mt = wave>>2, nt = wave&3) ----------
  {
    const int mt = wave >> 2, nt = wave & 3;
    const unsigned short* qp = qb + (size_t)(p0 + mt * 16 + l16) * DH + quad * 8;
    const int hrow = s0 - 16 + nt * 16 + l16;          // window row (per-lane)
    const bool hv = (hrow >= 0) && (hrow < SEQ);
    const unsigned short* hp = hb + (long long)(p0 - 16 + nt * 16 + l16) * DH + quad * 8;

    floatx4 ac[4] = {{0,0,0,0},{0,0,0,0},{0,0,0,0},{0,0,0,0}};
    const bf16x8 hz = {0,0,0,0,0,0,0,0};
    #pragma unroll
    for (int it = 0; it < 32; ++it) {                  // K = 1024, 32 bf16/step
      bf16x8 qa = *(const bf16x8*)(qp + it * 32);
      bf16x8 ha = hz;
      if (hv) ha = *(const bf16x8*)(hp + it * 32);
      ac[it & 3] = __builtin_amdgcn_mfma_f32_16x16x32_bf16(qa, ha, ac[it & 3], 0, 0, 0);
    }
    floatx4 s4;
    for (int r = 0; r < 4; r++)
      s4[r] = (ac[0][r] + ac[1][r]) + (ac[2][r] + ac[3][r]);
    for (int r = 0; r < 4; r++)
      Sf[(mt * 16 + quad * 4 + r) * 64 + nt * 16 + l16] = s4[r] * (1.f / 32.f);
  }
  __syncthreads();

  // ---------- softmax over the 33 band entries jj = row..row+32 ----------
  {
    const int row = tid >> 4, k = tid & 15;  // 16 threads per row
    const float v0 = Sf[row * 64 + row + k];
    const float v1 = Sf[row * 64 + row + k + 16];
    const float v2 = (k == 0) ? Sf[row * 64 + row + 32] : -1e30f;
    float mx = fmaxf(v0, fmaxf(v1, v2));
    for (int off = 1; off < 16; off <<= 1) mx = fmaxf(mx, __shfl_xor(mx, off, 64));
    const float e0 = __expf(v0 - mx), e1 = __expf(v1 - mx);
    const float e2 = (k == 0) ? __expf(v2 - mx) : 0.f;
    float sum = e0 + e1 + e2;
    for (int off = 1; off < 16; off <<= 1) sum += __shfl_xor(sum, off, 64);
    const float inv = 1.f / sum;
    Ps[row * 72 + row + k] = f2bf(e0 * inv);
    Ps[row * 72 + row + k + 16] = f2bf(e1 * inv);
    if (k == 0) Ps[row * 72 + row + 32] = f2bf(e2 * inv);
  }
  __syncthreads();

  // ---------- PV (transposed): D[dh, pos] = Hwin^T @ P^T ----------
  {
    const int nt2 = wave >> 2;  // pos half (0..1)
    const bf16x8 pb0 = *(const bf16x8*)&Ps[(nt2 * 16 + l16) * 72 + quad * 8];
    const bf16x8 pb1 = *(const bf16x8*)&Ps[(nt2 * 16 + l16) * 72 + 32 + quad * 8];

    int lo = 16 - s0; if (lo < 0) lo = 0;              // valid window-k range [lo,hi)
    int hi = SEQ + 16 - s0; if (hi > AW) hi = AW;
    const bool interior = (lo == 0) && (hi == AW);

    #pragma unroll
    for (int i = 0; i < 16; ++i) {
      const int mt2 = (wave & 3) * 16 + i;  // dh tile (0..63)
      const unsigned short* ap = hbT + (size_t)(mt2 * 16 + l16) * BS + (p0 - 16) + quad * 8;
      bf16x8 aa0 = *(const bf16x8*)(ap);
      bf16x8 aa1 = *(const bf16x8*)(ap + 32);
      if (!interior) {
        #pragma unroll
        for (int j = 0; j < 8; j++) {
          const int k = quad * 8 + j;
          if (k < lo || k >= hi) aa0[j] = 0;
          if (k + 32 < lo || k + 32 >= hi) aa1[j] = 0;
        }
      }
      floatx4 o = {0.f, 0.f, 0.f, 0.f};
      o = __builtin_amdgcn_mfma_f32_16x16x32_bf16(aa0, pb0, o, 0, 0, 0);
      o = __builtin_amdgcn_mfma_f32_16x16x32_bf16(aa1, pb1, o, 0, 0, 0);
      // C/D: col(l16)=pos, row(quad*4+r)=dh  ->  float4 store along dh
      float4 st; st.x = o[0]; st.y = o[1]; st.z = o[2]; st.w = o[3];
      *(float4*)(out + (size_t)(p0 + nt2 * 16 + l16) * DH + mt2 * 16 + quad * 4) = st;
    }
  }
}

extern "C" void kernel_launch(void* const* d_in, const int* in_sizes, int n_in,
                              void* d_out, int out_size, void* d_ws, size_t ws_size,
                              hipStream_t stream) {
  const float* x  = (const float*)d_in[0];
  const float* W1 = (const float*)d_in[1];
  const float* b1 = (const float*)d_in[2];
  const float* Wq = (const float*)d_in[3];

  // workspace layout (59 MB total)
  char* w = (char*)d_ws;
  unsigned short* xb  = (unsigned short*)(w);                  // 8 MB  x bf16
  unsigned short* w1t = (unsigned short*)(w + (8ull  << 20));  // 1 MB  W1^T bf16
  unsigned short* wqt = (unsigned short*)(w + (9ull  << 20));  // 2 MB  Wq^T bf16
  unsigned short* hb  = (unsigned short*)(w + (11ull << 20));  // 16 MB h bf16 row-major
  unsigned short* hbT = (unsigned short*)(w + (27ull << 20));  // 16 MB h bf16 transposed [DH][BS]
  unsigned short* qb  = (unsigned short*)(w + (43ull << 20));  // 16 MB q bf16 row-major

  to_bf16_k<<<(BS * DIN) / (256 * 4), 256, 0, stream>>>(x, xb, BS * DIN);
  transpose_bf16_k<<<dim3(DH / 32, DIN / 32), 256, 0, stream>>>(W1, w1t, DIN, DH);
  transpose_bf16_k<<<dim3(DH / 32, DH / 32), 256, 0, stream>>>(Wq, wqt, DH, DH);

  // h = relu(x @ W1 + b1)
  gemm_bt<true><<<dim3(DH / 128, BS / 128), 256, 0, stream>>>(xb, w1t, b1, hb, BS, DH, DIN);
  // hbT = h^T
  transpose_hb_k<<<dim3(BS / 64, DH / 64), 256, 0, stream>>>(hb, hbT);
  // q = h @ Wq
  gemm_bt<false><<<dim3(DH / 128, BS / 128), 256, 0, stream>>>(hb, wqt, nullptr, qb, BS, DH, DH);

  attn_mfma_k<<<BS / AP, 512, 0, stream>>>(hb, hbT, qb, (float*)d_out);
}

// Round 7
// 162.690 us; speedup vs baseline: 1.0711x; 1.0711x over previous
//
#include <hip/hip_runtime.h>
#include <stdint.h>

// Problem dims: x(4,2048,512) W1(512,1024) b1(1024) Wq(1024,1024) A=16 — fp32 in, fp32 out
constexpr int BATCH = 4;
constexpr int SEQ   = 2048;
constexpr int DIN   = 512;
constexpr int DH    = 1024;
constexpr int BS    = BATCH * SEQ;  // 8192
constexpr int AP    = 32;           // attn positions per block
constexpr int AW    = 64;           // attn window rows (AP + 2*16)

typedef float  floatx4 __attribute__((ext_vector_type(4)));
typedef short  bf16x8  __attribute__((ext_vector_type(8)));

static __device__ __forceinline__ unsigned short f2bf(float f) {
  union { float f; unsigned u; } v; v.f = f;
  unsigned r = (v.u + 0x7fffu + ((v.u >> 16) & 1u)) >> 16;  // RNE
  return (unsigned short)r;
}

// async global->LDS, 16B per lane; LDS dest is wave-uniform base + lane*16
static __device__ __forceinline__ void gld_lds16(const unsigned short* g, const short* l) {
  typedef const __attribute__((address_space(1))) void* gvp;
  typedef __attribute__((address_space(3))) void* lvp;
  __builtin_amdgcn_global_load_lds((gvp)(uintptr_t)g, (lvp)(unsigned)(uintptr_t)l, 16, 0, 0);
}

// ---------------- transpose fp32 (R x C) -> bf16 (C x R) ----------------
__global__ __launch_bounds__(256) void transpose_bf16_k(const float* __restrict__ in,
                                                        unsigned short* __restrict__ out,
                                                        int R, int C) {
  __shared__ float t[32][33];
  int c0 = blockIdx.x * 32, r0 = blockIdx.y * 32;
  int tx = threadIdx.x & 31, ty = threadIdx.x >> 5;  // 32 x 8
  for (int i = ty; i < 32; i += 8) t[i][tx] = in[(size_t)(r0 + i) * C + c0 + tx];
  __syncthreads();
  for (int i = ty; i < 32; i += 8) out[(size_t)(c0 + i) * R + r0 + tx] = f2bf(t[tx][i]);
}

// ---------------- GEMM1: h = relu(x @ W1 + b1), fused fp32->bf16 A-staging --------------
// 128x128 tile, BK=32. Grid: blockIdx.x = M-tile (64), blockIdx.y = N-tile (8) so that
// consecutive blocks (round-robin over XCDs) share the B strip and stream A once per XCD.
// Emits h row-major (hb) and transposed (hbT).
__global__ __launch_bounds__(256) void gemm1_k(const float* __restrict__ X,
                                               const unsigned short* __restrict__ Bt,
                                               const float* __restrict__ bias,
                                               unsigned short* __restrict__ outB,
                                               unsigned short* __restrict__ outBT) {
  const int M = BS, N = DH, K = DIN;
  __shared__ __align__(16) short As[128 * 32];
  __shared__ __align__(16) short Bs[128 * 32];
  const int tid  = threadIdx.x;
  const int m0   = blockIdx.x * 128, n0 = blockIdx.y * 128;
  const int wv   = tid >> 6, lane = tid & 63;
  const int wm   = (wv >> 1) * 64, wn = (wv & 1) * 64;
  const int l16  = lane & 15, quad = lane >> 4;

  // A staging: thread covers row ar = tid>>1, 16 fp32 starting at col (tid&1)*16
  const int ar = tid >> 1, acol = (tid & 1) * 16;
  const float* gX = X + (size_t)(m0 + ar) * K + acol;
  short* lA = &As[ar * 32 + acol];
  // B staging via global_load_lds (wave wv covers Bs rows wv*32..wv*32+31)
  const int ra = lane >> 2, ca = (lane & 3) * 8;
  const unsigned short* gB0 = Bt + (size_t)(n0 + wv * 32 + ra) * K + ca;
  const unsigned short* gB1 = Bt + (size_t)(n0 + wv * 32 + 16 + ra) * K + ca;
  const short* lB0 = &Bs[wv * 1024];
  const short* lB1 = &Bs[wv * 1024 + 512];

  floatx4 acc[4][4];
  for (int i = 0; i < 4; i++)
    for (int j = 0; j < 4; j++) acc[i][j] = {0.f, 0.f, 0.f, 0.f};

  for (int ks = 0; ks < K / 32; ++ks) {
    float4 x0 = ((const float4*)gX)[0], x1 = ((const float4*)gX)[1];
    float4 x2 = ((const float4*)gX)[2], x3 = ((const float4*)gX)[3];
    gX += 32;
    __syncthreads();  // prev iter LDS reads done
    gld_lds16(gB0, lB0); gld_lds16(gB1, lB1);
    gB0 += 32; gB1 += 32;
    __align__(16) unsigned short cv[16];
    cv[0] = f2bf(x0.x); cv[1] = f2bf(x0.y); cv[2]  = f2bf(x0.z); cv[3]  = f2bf(x0.w);
    cv[4] = f2bf(x1.x); cv[5] = f2bf(x1.y); cv[6]  = f2bf(x1.z); cv[7]  = f2bf(x1.w);
    cv[8] = f2bf(x2.x); cv[9] = f2bf(x2.y); cv[10] = f2bf(x2.z); cv[11] = f2bf(x2.w);
    cv[12] = f2bf(x3.x); cv[13] = f2bf(x3.y); cv[14] = f2bf(x3.z); cv[15] = f2bf(x3.w);
    ((uint4*)lA)[0] = ((uint4*)cv)[0];
    ((uint4*)lA)[1] = ((uint4*)cv)[1];
    __syncthreads();  // drains vmcnt + lgkmcnt before barrier
    bf16x8 af[4], bfr[4];
    for (int i = 0; i < 4; i++)
      af[i] = *(const bf16x8*)&As[(wm + i * 16 + l16) * 32 + quad * 8];
    for (int j = 0; j < 4; j++)
      bfr[j] = *(const bf16x8*)&Bs[(wn + j * 16 + l16) * 32 + quad * 8];
    for (int i = 0; i < 4; i++)
      for (int j = 0; j < 4; j++)
        acc[i][j] = __builtin_amdgcn_mfma_f32_16x16x32_bf16(af[i], bfr[j], acc[i][j], 0, 0, 0);
  }

  // epilogue: C row = m0+wm+i*16+quad*4+r, col = n0+wn+j*16+l16 (m89-verified C/D layout)
  for (int j = 0; j < 4; j++) {
    const int col = n0 + wn + j * 16 + l16;
    const float bv = bias[col];
    for (int i = 0; i < 4; i++) {
      const int rowb = m0 + wm + i * 16 + quad * 4;
      float v[4];
      for (int r = 0; r < 4; r++) v[r] = fmaxf(acc[i][j][r] + bv, 0.f);
      for (int r = 0; r < 4; r++) outB[(size_t)(rowb + r) * N + col] = f2bf(v[r]);
      ushort4 o4; o4.x = f2bf(v[0]); o4.y = f2bf(v[1]); o4.z = f2bf(v[2]); o4.w = f2bf(v[3]);
      *(ushort4*)(outBT + (size_t)col * M + rowb) = o4;  // transposed copy for attn PV
    }
  }
}

// ---------------- GEMM2: q = h @ Wq (bf16 A and B, both staged via global_load_lds) ------
__global__ __launch_bounds__(256) void gemm2_k(const unsigned short* __restrict__ Ab,
                                               const unsigned short* __restrict__ Bt,
                                               unsigned short* __restrict__ outB) {
  const int N = DH, K = DH;
  __shared__ __align__(16) short As[128 * 32];
  __shared__ __align__(16) short Bs[128 * 32];
  const int tid  = threadIdx.x;
  const int m0   = blockIdx.x * 128, n0 = blockIdx.y * 128;  // x = M-tile (XCD streaming)
  const int wv   = tid >> 6, lane = tid & 63;
  const int wm   = (wv >> 1) * 64, wn = (wv & 1) * 64;
  const int l16  = lane & 15, quad = lane >> 4;

  const int ra = lane >> 2, ca = (lane & 3) * 8;
  const unsigned short* gA0 = Ab + (size_t)(m0 + wv * 32 + ra) * K + ca;
  const unsigned short* gA1 = Ab + (size_t)(m0 + wv * 32 + 16 + ra) * K + ca;
  const unsigned short* gB0 = Bt + (size_t)(n0 + wv * 32 + ra) * K + ca;
  const unsigned short* gB1 = Bt + (size_t)(n0 + wv * 32 + 16 + ra) * K + ca;
  const short* lA0 = &As[wv * 1024];
  const short* lA1 = &As[wv * 1024 + 512];
  const short* lB0 = &Bs[wv * 1024];
  const short* lB1 = &Bs[wv * 1024 + 512];

  floatx4 acc[4][4];
  for (int i = 0; i < 4; i++)
    for (int j = 0; j < 4; j++) acc[i][j] = {0.f, 0.f, 0.f, 0.f};

  for (int ks = 0; ks < K / 32; ++ks) {
    __syncthreads();
    gld_lds16(gA0, lA0); gld_lds16(gA1, lA1);
    gld_lds16(gB0, lB0); gld_lds16(gB1, lB1);
    gA0 += 32; gA1 += 32; gB0 += 32; gB1 += 32;
    __syncthreads();
    bf16x8 af[4], bfr[4];
    for (int i = 0; i < 4; i++)
      af[i] = *(const bf16x8*)&As[(wm + i * 16 + l16) * 32 + quad * 8];
    for (int j = 0; j < 4; j++)
      bfr[j] = *(const bf16x8*)&Bs[(wn + j * 16 + l16) * 32 + quad * 8];
    for (int i = 0; i < 4; i++)
      for (int j = 0; j < 4; j++)
        acc[i][j] = __builtin_amdgcn_mfma_f32_16x16x32_bf16(af[i], bfr[j], acc[i][j], 0, 0, 0);
  }

  for (int j = 0; j < 4; j++) {
    const int col = n0 + wn + j * 16 + l16;
    for (int i = 0; i < 4; i++) {
      const int rowb = m0 + wm + i * 16 + quad * 4;
      for (int r = 0; r < 4; r++)
        outB[(size_t)(rowb + r) * N + col] = f2bf(acc[i][j][r]);
    }
  }
}

// ---------------- barrier-free MFMA banded attention (round-6 structure) ----------------
__global__ __launch_bounds__(512) void attn_mfma_k(const unsigned short* __restrict__ hb,
                                                   const unsigned short* __restrict__ hbT,
                                                   const unsigned short* __restrict__ qb,
                                                   float* __restrict__ out) {
  __shared__ float Sf[32 * 64];                // raw scores
  __shared__ __align__(16) short Ps[32 * 72];  // softmax weights, row=pos, col=window k

  const int tid  = threadIdx.x;
  const int wave = tid >> 6, lane = tid & 63;
  const int l16  = lane & 15, quad = lane >> 4;
  const int p0   = blockIdx.x * AP;
  const int s0   = p0 & (SEQ - 1);

  for (int i = tid; i < 32 * 72 / 2; i += 512) ((unsigned*)Ps)[i] = 0;

  // ---------- QK: S[32x64], wave -> tile (mt = wave>>2, nt = wave&3) ----------
  {
    const int mt = wave >> 2, nt = wave & 3;
    const unsigned short* qp = qb + (size_t)(p0 + mt * 16 + l16) * DH + quad * 8;
    const int hrow = s0 - 16 + nt * 16 + l16;          // window row (per-lane)
    const bool hv = (hrow >= 0) && (hrow < SEQ);
    const unsigned short* hp = hb + (long long)(p0 - 16 + nt * 16 + l16) * DH + quad * 8;

    floatx4 ac[4] = {{0,0,0,0},{0,0,0,0},{0,0,0,0},{0,0,0,0}};
    const bf16x8 hz = {0,0,0,0,0,0,0,0};
    #pragma unroll
    for (int it = 0; it < 32; ++it) {                  // K = 1024
      bf16x8 qa = *(const bf16x8*)(qp + it * 32);
      bf16x8 ha = hz;
      if (hv) ha = *(const bf16x8*)(hp + it * 32);
      ac[it & 3] = __builtin_amdgcn_mfma_f32_16x16x32_bf16(qa, ha, ac[it & 3], 0, 0, 0);
    }
    floatx4 s4;
    for (int r = 0; r < 4; r++)
      s4[r] = (ac[0][r] + ac[1][r]) + (ac[2][r] + ac[3][r]);
    for (int r = 0; r < 4; r++)
      Sf[(mt * 16 + quad * 4 + r) * 64 + nt * 16 + l16] = s4[r] * (1.f / 32.f);
  }
  __syncthreads();

  // ---------- softmax over the 33 band entries jj = row..row+32 ----------
  {
    const int row = tid >> 4, k = tid & 15;  // 16 threads per row
    const float v0 = Sf[row * 64 + row + k];
    const float v1 = Sf[row * 64 + row + k + 16];
    const float v2 = (k == 0) ? Sf[row * 64 + row + 32] : -1e30f;
    float mx = fmaxf(v0, fmaxf(v1, v2));
    for (int off = 1; off < 16; off <<= 1) mx = fmaxf(mx, __shfl_xor(mx, off, 64));
    const float e0 = __expf(v0 - mx), e1 = __expf(v1 - mx);
    const float e2 = (k == 0) ? __expf(v2 - mx) : 0.f;
    float sum = e0 + e1 + e2;
    for (int off = 1; off < 16; off <<= 1) sum += __shfl_xor(sum, off, 64);
    const float inv = 1.f / sum;
    Ps[row * 72 + row + k] = f2bf(e0 * inv);
    Ps[row * 72 + row + k + 16] = f2bf(e1 * inv);
    if (k == 0) Ps[row * 72 + row + 32] = f2bf(e2 * inv);
  }
  __syncthreads();

  // ---------- PV (transposed): D[dh, pos] = Hwin^T @ P^T ----------
  {
    const int nt2 = wave >> 2;  // pos half (0..1)
    const bf16x8 pb0 = *(const bf16x8*)&Ps[(nt2 * 16 + l16) * 72 + quad * 8];
    const bf16x8 pb1 = *(const bf16x8*)&Ps[(nt2 * 16 + l16) * 72 + 32 + quad * 8];

    int lo = 16 - s0; if (lo < 0) lo = 0;              // valid window-k range [lo,hi)
    int hi = SEQ + 16 - s0; if (hi > AW) hi = AW;
    const bool interior = (lo == 0) && (hi == AW);

    #pragma unroll
    for (int i = 0; i < 16; ++i) {
      const int mt2 = (wave & 3) * 16 + i;  // dh tile (0..63)
      const unsigned short* ap = hbT + (size_t)(mt2 * 16 + l16) * BS + (p0 - 16) + quad * 8;
      bf16x8 aa0 = *(const bf16x8*)(ap);
      bf16x8 aa1 = *(const bf16x8*)(ap + 32);
      if (!interior) {
        #pragma unroll
        for (int j = 0; j < 8; j++) {
          const int k = quad * 8 + j;
          if (k < lo || k >= hi) aa0[j] = 0;
          if (k + 32 < lo || k + 32 >= hi) aa1[j] = 0;
        }
      }
      floatx4 o = {0.f, 0.f, 0.f, 0.f};
      o = __builtin_amdgcn_mfma_f32_16x16x32_bf16(aa0, pb0, o, 0, 0, 0);
      o = __builtin_amdgcn_mfma_f32_16x16x32_bf16(aa1, pb1, o, 0, 0, 0);
      float4 st; st.x = o[0]; st.y = o[1]; st.z = o[2]; st.w = o[3];
      *(float4*)(out + (size_t)(p0 + nt2 * 16 + l16) * DH + mt2 * 16 + quad * 4) = st;
    }
  }
}

extern "C" void kernel_launch(void* const* d_in, const int* in_sizes, int n_in,
                              void* d_out, int out_size, void* d_ws, size_t ws_size,
                              hipStream_t stream) {
  const float* x  = (const float*)d_in[0];
  const float* W1 = (const float*)d_in[1];
  const float* b1 = (const float*)d_in[2];
  const float* Wq = (const float*)d_in[3];

  // workspace layout (51 MB total)
  char* w = (char*)d_ws;
  unsigned short* w1t = (unsigned short*)(w);                  // 1 MB  W1^T bf16
  unsigned short* wqt = (unsigned short*)(w + (1ull  << 20));  // 2 MB  Wq^T bf16
  unsigned short* hb  = (unsigned short*)(w + (3ull  << 20));  // 16 MB h bf16 row-major
  unsigned short* hbT = (unsigned short*)(w + (19ull << 20));  // 16 MB h bf16 transposed [DH][BS]
  unsigned short* qb  = (unsigned short*)(w + (35ull << 20));  // 16 MB q bf16 row-major

  transpose_bf16_k<<<dim3(DH / 32, DIN / 32), 256, 0, stream>>>(W1, w1t, DIN, DH);
  transpose_bf16_k<<<dim3(DH / 32, DH / 32), 256, 0, stream>>>(Wq, wqt, DH, DH);

  // h = relu(x @ W1 + b1), fused fp32->bf16; emits hb + hbT. Grid x = M-tile.
  gemm1_k<<<dim3(BS / 128, DH / 128), 256, 0, stream>>>(x, w1t, b1, hb, hbT);
  // q = h @ Wq. Grid x = M-tile.
  gemm2_k<<<dim3(BS / 128, DH / 128), 256, 0, stream>>>(hb, wqt, qb);

  attn_mfma_k<<<BS / AP, 512, 0, stream>>>(hb, hbT, qb, (float*)d_out);
}